// Round 4
// baseline (379.052 us; speedup 1.0000x reference)
//
#include <hip/hip_runtime.h>
#include <math.h>

#define T_TOKENS 16384
#define NEXP     64
#define KDIM     4096
#define TMB      32                  // tokens per block -> grid 512 (2-3 blocks/CU)
#define ROUNDS   32                  // 128 k per round

typedef _Float16 f16;
typedef f16   f16x2 __attribute__((ext_vector_type(2)));
typedef f16   f16x8 __attribute__((ext_vector_type(8)));
typedef float f32x4 __attribute__((ext_vector_type(4)));

// split 8 fp32 -> packed fp16 hi (uint4) and lo*2^11 (uint4)
__device__ __forceinline__ void split8(const float v[8], uint4* ho, uint4* lo) {
    unsigned hu[4], lu[4];
    #pragma unroll
    for (int p = 0; p < 4; ++p) {
        f16x2 h2, l2;
#if __has_builtin(__builtin_amdgcn_cvt_pkrtz)
        h2 = __builtin_bit_cast(f16x2, __builtin_amdgcn_cvt_pkrtz(v[2*p], v[2*p+1]));
#else
        h2.x = (f16)v[2*p]; h2.y = (f16)v[2*p+1];
#endif
        float r0 = (v[2*p]   - (float)h2.x) * 2048.0f;
        float r1 = (v[2*p+1] - (float)h2.y) * 2048.0f;
#if __has_builtin(__builtin_amdgcn_cvt_pkrtz)
        l2 = __builtin_bit_cast(f16x2, __builtin_amdgcn_cvt_pkrtz(r0, r1));
#else
        l2.x = (f16)r0; l2.y = (f16)r1;
#endif
        hu[p] = __builtin_bit_cast(unsigned, h2);
        lu[p] = __builtin_bit_cast(unsigned, l2);
    }
    *ho = make_uint4(hu[0], hu[1], hu[2], hu[3]);
    *lo = make_uint4(lu[0], lu[1], lu[2], lu[3]);
}

__device__ __forceinline__ f16x8 asf16x8(uint4 u) {
    return __builtin_bit_cast(f16x8, u);
}

// LDS unit-index (16B units) XOR swizzle: fold the k32-step s into lane bits
// 1-2 so staging writes (bank quad was row&7 only: 16-way) and frag reads both
// hit the 8-cycle wave64 b128 floor. Key bits: A-frag index fa=s*4+fmt*2+mt
// -> s at u bits 8-9; B-frag index fb=s*8+fmt*4+nt -> s at u bits 9-10.
__device__ __forceinline__ int swzA(int u) { return u ^ (((u >> 8) & 3) << 1); }
__device__ __forceinline__ int swzB(int u) { return u ^ (((u >> 9) & 3) << 1); }

// ---------------------------------------------------------------------------
// 512 blocks x 512 thr (8 waves). Block = 32 tokens x 64 experts, full K.
// Wave wid: mt = wid>>2 (token tile of 16), nt = wid&3 (expert tile of 16).
// Each wave owns ONE 16x16 output tile over the FULL K: acc = 2 f32x4, no
// cross-wave K reduction. Per round (128 k): 512 threads cooperatively stage
// x-slice [32 tok][128 k] and W-slice [64 exp][128 k] fp32 -> f16 hi/lo MFMA
// frags in LDS (48 KB -> 3 blocks/CU by LDS; grid 512 -> >=2 blocks/CU, which
// hides the compiler's vmcnt(0) drain at each barrier).
// Frag content (verified in R0-R3 kernels):
//   A/B lane l, elem j: row = tile*16+(l&15), k = s*32 + (l>>4)*8 + j
//   C/D: col(expert) = lane&15, row(token) = (lane>>4)*4 + rr
// logit*64 = acc_hh + acc_lo/2048 (W scaled x64 at conversion).
// ---------------------------------------------------------------------------
__global__ __launch_bounds__(512, 4) void router_mfma(
    const float* __restrict__ x, const float* __restrict__ W,
    float* __restrict__ out)
{
    __shared__ __align__(16) unsigned char sm[49152];
    unsigned char* As = sm;           // 16 KB: 16 frags (s,fmt,mt) x 64 lanes x 16B
    unsigned char* Bs = sm + 16384;   // 32 KB: 32 frags (s,fmt,nt) x 64 lanes x 16B

    const int tid  = threadIdx.x;
    const int wid  = tid >> 6;
    const int lane = tid & 63;
    const int mt   = wid >> 2;            // token tile 0..1
    const int nt   = wid & 3;             // expert tile 0..3
    const int t0   = blockIdx.x * TMB;

    // ---- x staging identity: 8 floats/thread (one split8) ----
    const int xrow = tid >> 4;            // 0..31
    const int xkl  = (tid & 15) * 8;      // k offset within 128-slice
    const float* xsrc = x + (size_t)(t0 + xrow) * KDIM + xkl;
    int xu_hi, xu_lo;
    {
        int s  = xkl >> 5;
        int j3 = (xkl >> 3) & 3;
        int lf = j3 * 16 + (xrow & 15);
        int fa = s * 4 + (xrow >> 4);     // fmt=0
        xu_hi = swzA(fa * 64 + lf) * 16;
        xu_lo = swzA((fa + 2) * 64 + lf) * 16;
    }

    // ---- W staging identity: 16 floats/thread (two split8 groups) ----
    const int erow = tid >> 3;            // 0..63
    const int wk0  = (tid & 7) * 16;
    const float* wsrc = W + (size_t)erow * KDIM + wk0;
    int wu_hi[2], wu_lo[2];
    #pragma unroll
    for (int g = 0; g < 2; ++g) {
        int kl = wk0 + g * 8;
        int s  = kl >> 5;
        int j3 = (kl >> 3) & 3;
        int lf = j3 * 16 + (erow & 15);
        int fb = s * 8 + (erow >> 4);     // fmt=0
        wu_hi[g] = swzB(fb * 64 + lf) * 16;
        wu_lo[g] = swzB((fb + 4) * 64 + lf) * 16;
    }

    // ---- frag read byte offsets per k32 step s ----
    int ua_hi[4], ua_lo[4], ub_hi[4], ub_lo[4];
    #pragma unroll
    for (int s = 0; s < 4; ++s) {
        ua_hi[s] = swzA((s * 4 + mt) * 64 + lane) * 16;
        ua_lo[s] = swzA((s * 4 + 2 + mt) * 64 + lane) * 16;
        ub_hi[s] = swzB((s * 8 + nt) * 64 + lane) * 16;
        ub_lo[s] = swzB((s * 8 + 4 + nt) * 64 + lane) * 16;
    }

    f32x4 acc_hh = (f32x4){0.f, 0.f, 0.f, 0.f};
    f32x4 acc_lo = (f32x4){0.f, 0.f, 0.f, 0.f};

    // prologue: round-0 slices -> regs
    float4 xc[2], wc[4], xn[2], wn[4];
    xc[0] = *(const float4*)(xsrc);
    xc[1] = *(const float4*)(xsrc + 4);
    #pragma unroll
    for (int q = 0; q < 4; ++q) wc[q] = *(const float4*)(wsrc + q * 4);

    for (int r = 0; r < ROUNDS; ++r) {
        // ---- convert + write current slices into frag LDS ----
        {
            float v[8] = { xc[0].x, xc[0].y, xc[0].z, xc[0].w,
                           xc[1].x, xc[1].y, xc[1].z, xc[1].w };
            uint4 ho, lo;
            split8(v, &ho, &lo);
            *(uint4*)(As + xu_hi) = ho;
            *(uint4*)(As + xu_lo) = lo;
        }
        #pragma unroll
        for (int g = 0; g < 2; ++g) {
            float v[8] = { wc[2*g].x * 64.f,   wc[2*g].y * 64.f,
                           wc[2*g].z * 64.f,   wc[2*g].w * 64.f,
                           wc[2*g+1].x * 64.f, wc[2*g+1].y * 64.f,
                           wc[2*g+1].z * 64.f, wc[2*g+1].w * 64.f };
            uint4 ho, lo;
            split8(v, &ho, &lo);
            *(uint4*)(Bs + wu_hi[g]) = ho;
            *(uint4*)(Bs + wu_lo[g]) = lo;
        }
        __syncthreads();   // B1: frags ready (only lgkm outstanding here)

        // ---- issue next-round global loads inside B1->B2 window ----
        if (r + 1 < ROUNDS) {
            const float* xp = xsrc + (r + 1) * 128;
            const float* wp = wsrc + (r + 1) * 128;
            xn[0] = *(const float4*)(xp);
            xn[1] = *(const float4*)(xp + 4);
            #pragma unroll
            for (int q = 0; q < 4; ++q) wn[q] = *(const float4*)(wp + q * 4);
        }

        // ---- MFMA: 4 k32 steps x 3 passes ----
        #pragma unroll
        for (int s = 0; s < 4; ++s) {
            f16x8 ah = asf16x8(*(const uint4*)(As + ua_hi[s]));
            f16x8 al = asf16x8(*(const uint4*)(As + ua_lo[s]));
            f16x8 bh = asf16x8(*(const uint4*)(Bs + ub_hi[s]));
            f16x8 bl = asf16x8(*(const uint4*)(Bs + ub_lo[s]));
            acc_hh = __builtin_amdgcn_mfma_f32_16x16x32_f16(ah, bh, acc_hh, 0, 0, 0);
            acc_lo = __builtin_amdgcn_mfma_f32_16x16x32_f16(ah, bl, acc_lo, 0, 0, 0);
            acc_lo = __builtin_amdgcn_mfma_f32_16x16x32_f16(al, bh, acc_lo, 0, 0, 0);
        }
        __syncthreads();   // B2: frags consumed; prefetch drains here

        if (r + 1 < ROUNDS) {
            xc[0] = xn[0]; xc[1] = xn[1];
            #pragma unroll
            for (int q = 0; q < 4; ++q) wc[q] = wn[q];
        }
    }

    // ---- epilogue: each wave owns full-K tile; write logits, top-2 ----
    float (*partial)[69] = (float (*)[69])sm;   // [32][69] floats, aliases As
    #pragma unroll
    for (int rr = 0; rr < 4; ++rr) {
        int token = mt * 16 + (lane >> 4) * 4 + rr;
        int e     = nt * 16 + (lane & 15);
        partial[token][e] = acc_hh[rr] + acc_lo[rr] * (1.0f / 2048.0f);
    }
    __syncthreads();

    if (tid < TMB) {
        const int t = tid;
        float m1 = -INFINITY, m2 = -INFINITY;
        int i1 = 0, i2 = 0;
        for (int e = 0; e < NEXP; ++e) {
            float v = partial[t][e];
            if (v > m1)      { m2 = m1; i2 = i1; m1 = v; i1 = e; }
            else if (v > m2) { m2 = v; i2 = e; }
        }
        float e2 = __expf((m2 - m1) * (1.0f / 64.0f));  // undo x64 W scale
        float denom = 1.f + e2;
        int gt = t0 + t;
        out[gt * 2 + 0] = 1.f / denom;
        out[gt * 2 + 1] = e2 / denom;
        out[2 * T_TOKENS + gt * 2 + 0] = (float)i1;
        out[2 * T_TOKENS + gt * 2 + 1] = (float)i2;
    }
}

extern "C" void kernel_launch(void* const* d_in, const int* in_sizes, int n_in,
                              void* d_out, int out_size, void* d_ws, size_t ws_size,
                              hipStream_t stream) {
    const float* x = (const float*)d_in[0];
    const float* W = (const float*)d_in[1];
    (void)d_ws; (void)ws_size;   // ws poison is unconditional; still avoid extra traffic

    router_mfma<<<T_TOKENS / TMB, 512, 0, stream>>>(x, W, (float*)d_out);
}

// Round 5
// 376.761 us; speedup vs baseline: 1.0061x; 1.0061x over previous
//
#include <hip/hip_runtime.h>
#include <math.h>

#define T_TOKENS 16384
#define NEXP     64
#define KDIM     4096
#define TMB      64                  // tokens per block -> grid 256
#define ROUNDS   32                  // 128 k per round (64 per K-half wave)

typedef _Float16 f16;
typedef f16   f16x2 __attribute__((ext_vector_type(2)));
typedef f16   f16x8 __attribute__((ext_vector_type(8)));
typedef float f32x4 __attribute__((ext_vector_type(4)));

// split 8 fp32 -> packed fp16 hi (uint4) and lo*2^11 (uint4)
__device__ __forceinline__ void split8(const float v[8], uint4* ho, uint4* lo) {
    unsigned hu[4], lu[4];
    #pragma unroll
    for (int p = 0; p < 4; ++p) {
        f16x2 h2, l2;
#if __has_builtin(__builtin_amdgcn_cvt_pkrtz)
        h2 = __builtin_bit_cast(f16x2, __builtin_amdgcn_cvt_pkrtz(v[2*p], v[2*p+1]));
#else
        h2.x = (f16)v[2*p]; h2.y = (f16)v[2*p+1];
#endif
        float r0 = (v[2*p]   - (float)h2.x) * 2048.0f;
        float r1 = (v[2*p+1] - (float)h2.y) * 2048.0f;
#if __has_builtin(__builtin_amdgcn_cvt_pkrtz)
        l2 = __builtin_bit_cast(f16x2, __builtin_amdgcn_cvt_pkrtz(r0, r1));
#else
        l2.x = (f16)r0; l2.y = (f16)r1;
#endif
        hu[p] = __builtin_bit_cast(unsigned, h2);
        lu[p] = __builtin_bit_cast(unsigned, l2);
    }
    *ho = make_uint4(hu[0], hu[1], hu[2], hu[3]);
    *lo = make_uint4(lu[0], lu[1], lu[2], lu[3]);
}

__device__ __forceinline__ f16x8 asf16x8(uint4 u) {
    return __builtin_bit_cast(f16x8, u);
}

// ---------------------------------------------------------------------------
// 256 blocks x 512 thr (8 waves). Block = 64 tokens x 64 experts, full K.
// Wave wid: mt = wid>>1 (token tile of 16), hq = wid&1 (K-half of each 128-k
// round). Key changes vs R3 (router ~112 us):
//  (1) x bypasses LDS entirely: the A-frag mapping (row = mt*16+(lane&15),
//      k = hq*64 + s*32 + (lane>>4)*8 + j) makes each lane's 8 A-elements
//      8 contiguous floats of one x row -> loaded as 2x dwordx4 straight from
//      global (16 cache lines/wave, each line owned by one wave), converted
//      to f16 hi/lo in-register. Halves LDS traffic, removes x staging.
//  (2) W LDS is double-buffered (2 x 32 KB): round r MFMAs from buf[r&1]
//      while converting+writing W slice r+1 into buf[r&1^1] -> ONE barrier
//      per round (32 total vs 64), staging overlapped with MFMA.
//  (3) 1-round-deep register prefetch for both x and W covers the vmcnt
//      drain at the barrier.
// B-frag LDS layout identical to R3 (verified): frag fb = ((h*2+s)*2+fmt)*4+nt,
// unit = fb*64 + lane_f, bank-uniform on both write and read.
// logit*64 = acc_hh + acc_lo/2048 (W scaled x64 at conversion).
// ---------------------------------------------------------------------------
__global__ __launch_bounds__(512, 2) void router_mfma(
    const float* __restrict__ x, const float* __restrict__ W,
    float* __restrict__ out)
{
    __shared__ __align__(16) unsigned char Bs[2][32768];

    const int tid  = threadIdx.x;
    const int wid  = tid >> 6;
    const int lane = tid & 63;
    const int mt   = wid >> 1;            // token tile 0..3
    const int hq   = wid & 1;             // K-half 0..1
    const int t0   = blockIdx.x * TMB;

    // ---- x direct A-frag pointer: 8 contiguous floats per lane per k32 ----
    const float* xp = x + (size_t)(t0 + mt * 16 + (lane & 15)) * KDIM
                    + hq * 64 + ((lane >> 4) << 3);

    // ---- W staging identity: 16 floats/thread/round (two split8 groups) ----
    const int erow = tid >> 3;            // 0..63 (expert row)
    const int wk0  = (tid & 7) * 16;      // k offset within 128-slice
    const float* wp = W + (size_t)erow * KDIM + wk0;
    int wu_hi[2], wu_lo[2];               // byte offsets within one 32 KB buf
    #pragma unroll
    for (int g = 0; g < 2; ++g) {
        int kl = wk0 + g * 8;
        int h  = (kl >> 6) & 1;
        int s5 = (kl >> 5) & 1;
        int j3 = (kl >> 3) & 3;
        int lf = j3 * 16 + (erow & 15);
        int fb = ((h * 2 + s5) * 2 + 0) * 4 + (erow >> 4);   // fmt=0
        wu_hi[g] = (fb * 64 + lf) * 16;
        wu_lo[g] = ((fb + 4) * 64 + lf) * 16;                // fmt=1: +4 frags
    }

    // ---- B-frag read byte offsets per k32 step s (nt adds 1024, lo +4096) ----
    int ub[2];
    #pragma unroll
    for (int s = 0; s < 2; ++s)
        ub[s] = ((((hq * 2 + s) * 2 + 0) * 4 + 0) * 64 + lane) * 16;

    f32x4 acc_hh[4], acc_lo[4];
    #pragma unroll
    for (int nt = 0; nt < 4; ++nt) {
        acc_hh[nt] = (f32x4){0.f, 0.f, 0.f, 0.f};
        acc_lo[nt] = (f32x4){0.f, 0.f, 0.f, 0.f};
    }

    // ---- prologue ----
    float4 w0r[4], wc[4];                 // W slice 0 (stage now) / slice 1
    #pragma unroll
    for (int q = 0; q < 4; ++q) w0r[q] = *(const float4*)(wp + q * 4);
    float4 xc[2][2], xn[2][2];            // x frags round 0 / round 1
    xc[0][0] = *(const float4*)(xp);        xc[0][1] = *(const float4*)(xp + 4);
    xc[1][0] = *(const float4*)(xp + 32);   xc[1][1] = *(const float4*)(xp + 36);
    #pragma unroll
    for (int g = 0; g < 2; ++g) {
        float v[8] = { w0r[2*g].x * 64.f,   w0r[2*g].y * 64.f,
                       w0r[2*g].z * 64.f,   w0r[2*g].w * 64.f,
                       w0r[2*g+1].x * 64.f, w0r[2*g+1].y * 64.f,
                       w0r[2*g+1].z * 64.f, w0r[2*g+1].w * 64.f };
        uint4 ho, lo;
        split8(v, &ho, &lo);
        *(uint4*)(Bs[0] + wu_hi[g]) = ho;
        *(uint4*)(Bs[0] + wu_lo[g]) = lo;
    }
    #pragma unroll
    for (int q = 0; q < 4; ++q) wc[q] = *(const float4*)(wp + 128 + q * 4);
    xn[0][0] = *(const float4*)(xp + 128);  xn[0][1] = *(const float4*)(xp + 132);
    xn[1][0] = *(const float4*)(xp + 160);  xn[1][1] = *(const float4*)(xp + 164);
    __syncthreads();                      // buf0 ready

    // invariant at top of round r: Bs[r&1] = W slice r; wc = W slice r+1;
    // xc = x frags round r; xn = x frags round r+1 (in flight or arrived)
    #pragma unroll 2
    for (int r = 0; r < ROUNDS; ++r) {
        const unsigned char* bcur = Bs[r & 1];
        unsigned char*       bnxt = (unsigned char*)Bs[(r + 1) & 1];

        // ---- MFMA phase: in-reg x convert + LDS B reads, 24 MFMAs ----
        #pragma unroll
        for (int s = 0; s < 2; ++s) {
            float v[8] = { xc[s][0].x, xc[s][0].y, xc[s][0].z, xc[s][0].w,
                           xc[s][1].x, xc[s][1].y, xc[s][1].z, xc[s][1].w };
            uint4 ahu, alu;
            split8(v, &ahu, &alu);
            f16x8 ah = asf16x8(ahu);
            f16x8 al = asf16x8(alu);
            #pragma unroll
            for (int nt = 0; nt < 4; ++nt) {
                f16x8 bh = asf16x8(*(const uint4*)(bcur + ub[s] + nt * 1024));
                f16x8 bl = asf16x8(*(const uint4*)(bcur + ub[s] + nt * 1024 + 4096));
                acc_hh[nt] = __builtin_amdgcn_mfma_f32_16x16x32_f16(ah, bh, acc_hh[nt], 0, 0, 0);
                acc_lo[nt] = __builtin_amdgcn_mfma_f32_16x16x32_f16(ah, bl, acc_lo[nt], 0, 0, 0);
                acc_lo[nt] = __builtin_amdgcn_mfma_f32_16x16x32_f16(al, bh, acc_lo[nt], 0, 0, 0);
            }
        }

        // ---- stage phase: convert wc (slice r+1) -> bnxt ----
        #pragma unroll
        for (int g = 0; g < 2; ++g) {
            float v[8] = { wc[2*g].x * 64.f,   wc[2*g].y * 64.f,
                           wc[2*g].z * 64.f,   wc[2*g].w * 64.f,
                           wc[2*g+1].x * 64.f, wc[2*g+1].y * 64.f,
                           wc[2*g+1].z * 64.f, wc[2*g+1].w * 64.f };
            uint4 ho, lo;
            split8(v, &ho, &lo);
            *(uint4*)(bnxt + wu_hi[g]) = ho;
            *(uint4*)(bnxt + wu_lo[g]) = lo;
        }

        // ---- register rotation + prefetch round r+2 ----
        xc[0][0] = xn[0][0]; xc[0][1] = xn[0][1];
        xc[1][0] = xn[1][0]; xc[1][1] = xn[1][1];
        if (r + 2 < ROUNDS) {
            const float* xq = xp + (r + 2) * 128;
            xn[0][0] = *(const float4*)(xq);       xn[0][1] = *(const float4*)(xq + 4);
            xn[1][0] = *(const float4*)(xq + 32);  xn[1][1] = *(const float4*)(xq + 36);
            const float* wq = wp + (r + 2) * 128;
            #pragma unroll
            for (int q = 0; q < 4; ++q) wc[q] = *(const float4*)(wq + q * 4);
        }
        __syncthreads();   // bnxt ready for round r+1; bcur free for r+2 writes
    }

    // ---- epilogue: per-K-half partial logits (x64-scaled), 2-way sum, top-2 ----
    float (*partial)[64][69] = (float (*)[64][69])Bs;   // 35328 B, aliases Bs
    #pragma unroll
    for (int nt = 0; nt < 4; ++nt) {
        #pragma unroll
        for (int rr = 0; rr < 4; ++rr) {
            int token = mt * 16 + (lane >> 4) * 4 + rr;
            int e     = nt * 16 + (lane & 15);
            partial[hq][token][e] = acc_hh[nt][rr] + acc_lo[nt][rr] * (1.0f / 2048.0f);
        }
    }
    __syncthreads();

    if (tid < TMB) {
        const int t = tid;
        float m1 = -INFINITY, m2 = -INFINITY;
        int i1 = 0, i2 = 0;
        for (int e = 0; e < NEXP; ++e) {
            float v = partial[0][t][e] + partial[1][t][e];
            if (v > m1)      { m2 = m1; i2 = i1; m1 = v; i1 = e; }
            else if (v > m2) { m2 = v; i2 = e; }
        }
        float e2 = __expf((m2 - m1) * (1.0f / 64.0f));  // undo x64 W scale
        float denom = 1.f + e2;
        int gt = t0 + t;
        out[gt * 2 + 0] = 1.f / denom;
        out[gt * 2 + 1] = e2 / denom;
        out[2 * T_TOKENS + gt * 2 + 0] = (float)i1;
        out[2 * T_TOKENS + gt * 2 + 1] = (float)i2;
    }
}

extern "C" void kernel_launch(void* const* d_in, const int* in_sizes, int n_in,
                              void* d_out, int out_size, void* d_ws, size_t ws_size,
                              hipStream_t stream) {
    const float* x = (const float*)d_in[0];
    const float* W = (const float*)d_in[1];
    (void)d_ws; (void)ws_size;   // ws poison is unconditional; avoid extra traffic

    router_mfma<<<T_TOKENS / TMB, 512, 0, stream>>>(x, W, (float*)d_out);
}